// Round 7
// baseline (304.213 us; speedup 1.0000x reference)
//
#include <hip/hip_runtime.h>
#include <hip/hip_bf16.h>
#include <math.h>

#define V 100000
#define H 256
#define B 512

typedef __bf16 bf16x8 __attribute__((ext_vector_type(8)));
typedef float  f32x4  __attribute__((ext_vector_type(4)));

__device__ __forceinline__ unsigned short f32_bf16_rne(float x) {
    unsigned u = __float_as_uint(x);
    u += 0x7FFFu + ((u >> 16) & 1u);            // round-to-nearest-even
    return (unsigned short)(u >> 16);
}
__device__ __forceinline__ float bf16u_f32(unsigned short h) {
    return __uint_as_float(((unsigned)h) << 16);
}
__device__ __forceinline__ float fast_tanh(float x) {
    // tanh(x) = 1 - 2/(exp2(x*2*log2e)+1); saturates correctly at +-inf
    float e = __builtin_exp2f(x * 2.8853900817779268f);
    return 1.f - 2.f * __builtin_amdgcn_rcpf(e + 1.f);
}

// ---------------------------------------------------------------------------
// Kernel 1: GRU cell (proven rounds 3-6). One block per batch element; writes
// h_new into d_out + B*V, plus bf16 hi/lo planes of h_new into workspace.
// ---------------------------------------------------------------------------
__global__ __launch_bounds__(256) void gru_cell_kernel(
    const int*   __restrict__ input,
    const float* __restrict__ hidden,
    const float* __restrict__ w_ih,
    const float* __restrict__ w_hh,
    const float* __restrict__ b_ih,
    const float* __restrict__ b_hh,
    float*       __restrict__ h_out,
    unsigned short* __restrict__ h_hi_p,   // may be null (fallback path)
    unsigned short* __restrict__ h_lo_p)
{
    const int b = blockIdx.x;
    const int j = threadIdx.x;

    __shared__ float hs[H];
    hs[j] = hidden[b * H + j];
    __syncthreads();

    const int idx = input[b];
    float gi_r = w_ih[ j          * V + idx] + b_ih[j];
    float gi_z = w_ih[(j +     H) * V + idx] + b_ih[j + H];
    float gi_n = w_ih[(j + 2 * H) * V + idx] + b_ih[j + 2 * H];

    const float4* wr = reinterpret_cast<const float4*>(&w_hh[ j          * H]);
    const float4* wz = reinterpret_cast<const float4*>(&w_hh[(j +     H) * H]);
    const float4* wn = reinterpret_cast<const float4*>(&w_hh[(j + 2 * H) * H]);
    const float4* h4 = reinterpret_cast<const float4*>(hs);

    float ar = 0.f, az = 0.f, an = 0.f;
    #pragma unroll 8
    for (int k = 0; k < H / 4; ++k) {
        const float4 hv = h4[k];
        const float4 a  = wr[k];
        const float4 c  = wz[k];
        const float4 d  = wn[k];
        ar += a.x * hv.x + a.y * hv.y + a.z * hv.z + a.w * hv.w;
        az += c.x * hv.x + c.y * hv.y + c.z * hv.z + c.w * hv.w;
        an += d.x * hv.x + d.y * hv.y + d.z * hv.z + d.w * hv.w;
    }

    const float h_r = ar + b_hh[j];
    const float h_z = az + b_hh[j + H];
    const float h_n = an + b_hh[j + 2 * H];

    const float r = 1.f / (1.f + expf(-(gi_r + h_r)));
    const float z = 1.f / (1.f + expf(-(gi_z + h_z)));
    const float n = tanhf(gi_n + r * h_n);
    const float hprev = hs[j];

    const float val = (1.f - z) * n + z * hprev;
    h_out[b * H + j] = val;
    if (h_hi_p != nullptr) {
        const unsigned short hh = f32_bf16_rne(val);
        h_hi_p[b * H + j] = hh;
        h_lo_p[b * H + j] = f32_bf16_rne(val - bf16u_f32(hh));
    }
}

// ---------------------------------------------------------------------------
// Kernel 2 (new structure): persistent vocab-stripe GEMM.
// Block = 64 vocab rows x ALL 512 batches; 256 threads = 4 waves, each wave
// owns 128 batches x 64 vocab (acc[8][4] f32x4 = 128 VGPR). Loop over K in 4
// chunks of 64:
//   - w_out fp32 chunk (64x64) prefetched to regs one chunk ahead (issue-early),
//     hi/lo-split + ds_write at chunk start (w read ONCE from HBM, split ONCE),
//   - h read per-lane straight from pre-split bf16 planes in L2 (no LDS),
//   - 192 MFMA/wave/chunk vs one 16 KB stage -> stage latency amortized 8x
//     better than the previous per-batch-block kernel.
// Fragment layout / swizzle / store mapping identical to the verified path.
// ---------------------------------------------------------------------------
#define VT  64
#define BK  64
#define NVB2 1563   // ceil(V/VT)

__global__ __launch_bounds__(256, 2) void out_gemm_fused(
    const float*          __restrict__ w_out,  // (V,H) fp32
    const unsigned short* __restrict__ hhi_g,  // (B,H) bf16 hi plane
    const unsigned short* __restrict__ hlo_g,  // (B,H) bf16 lo plane
    const float*          __restrict__ b_out,  // (V)
    float*                __restrict__ logit)  // (B,V)
{
    __shared__ unsigned short w_hi_s[VT * BK];   // 8 KB
    __shared__ unsigned short w_lo_s[VT * BK];   // 8 KB

    const int tid  = threadIdx.x;
    const int lane = tid & 63;
    const int wid  = tid >> 6;              // wave id 0..3 -> batch quarter
    const int v0   = blockIdx.x * VT;

    float4 wreg[4];

    auto load_w = [&](int k0) {
        #pragma unroll
        for (int i = 0; i < 4; ++i) {
            const int u   = i * 256 + tid;
            const int row = u >> 4;          // 0..63 local vocab row
            const int k4  = (u & 15) << 2;   // 0..60
            int vg = v0 + row; if (vg > V - 1) vg = V - 1;  // clamp; masked store
            wreg[i] = *reinterpret_cast<const float4*>(&w_out[(size_t)vg * H + k0 + k4]);
        }
    };

    auto store_w = [&]() {
        #pragma unroll
        for (int i = 0; i < 4; ++i) {
            const int u   = i * 256 + tid;
            const int row = u >> 4;
            const int k4  = (u & 15) << 2;
            const int off = row * (BK * 2) + ((k4 * 2) ^ ((row & 7) << 4));
            const float f[4] = {wreg[i].x, wreg[i].y, wreg[i].z, wreg[i].w};
            unsigned short hv[4], lv[4];
            #pragma unroll
            for (int j = 0; j < 4; ++j) {
                hv[j] = f32_bf16_rne(f[j]);
                lv[j] = f32_bf16_rne(f[j] - bf16u_f32(hv[j]));
            }
            *reinterpret_cast<ushort4*>(reinterpret_cast<char*>(w_hi_s) + off) =
                make_ushort4(hv[0], hv[1], hv[2], hv[3]);
            *reinterpret_cast<ushort4*>(reinterpret_cast<char*>(w_lo_s) + off) =
                make_ushort4(lv[0], lv[1], lv[2], lv[3]);
        }
    };

    f32x4 acc[8][4];
    #pragma unroll
    for (int m = 0; m < 8; ++m)
        #pragma unroll
        for (int n = 0; n < 4; ++n)
            acc[m][n] = f32x4{0.f, 0.f, 0.f, 0.f};

    auto compute = [&](int t) {
        #pragma unroll
        for (int ks = 0; ks < 2; ++ks) {
            const int kb = ks * 64 + (lane >> 4) * 16;   // LDS k byte offset
            bf16x8 bh[4], bl[4];
            #pragma unroll
            for (int n = 0; n < 4; ++n) {
                const int row = n * 16 + (lane & 15);
                const int off = row * (BK * 2) + (kb ^ ((row & 7) << 4));
                bh[n] = *reinterpret_cast<const bf16x8*>(
                            reinterpret_cast<const char*>(w_hi_s) + off);
                bl[n] = *reinterpret_cast<const bf16x8*>(
                            reinterpret_cast<const char*>(w_lo_s) + off);
            }
            // A fragments straight from bf16 h planes (L2-resident, 16B/lane)
            const size_t hb = ((size_t)(wid * 128 + (lane & 15)) * H
                               + t * BK + ks * 32 + (lane >> 4) * 8) * 2;
            #pragma unroll
            for (int m = 0; m < 8; ++m) {
                const size_t ho = hb + (size_t)(m * 16) * (H * 2);
                const bf16x8 ah = *reinterpret_cast<const bf16x8*>(
                            reinterpret_cast<const char*>(hhi_g) + ho);
                const bf16x8 al = *reinterpret_cast<const bf16x8*>(
                            reinterpret_cast<const char*>(hlo_g) + ho);
                #pragma unroll
                for (int n = 0; n < 4; ++n) {
                    acc[m][n] = __builtin_amdgcn_mfma_f32_16x16x32_bf16(ah, bh[n], acc[m][n], 0, 0, 0);
                    acc[m][n] = __builtin_amdgcn_mfma_f32_16x16x32_bf16(ah, bl[n], acc[m][n], 0, 0, 0);
                    acc[m][n] = __builtin_amdgcn_mfma_f32_16x16x32_bf16(al, bh[n], acc[m][n], 0, 0, 0);
                }
            }
        }
    };

    load_w(0);
    #pragma unroll
    for (int t = 0; t < 4; ++t) {
        store_w();                      // convert wreg -> LDS hi/lo
        __syncthreads();                // LDS visible
        if (t < 3) load_w((t + 1) * BK); // issue next chunk early; lands under MFMA
        compute(t);
        __syncthreads();                // reads done before next overwrite
    }

    // Epilogue: bias + tanh + masked store. C/D: col=lane&15, row=(lane>>4)*4+r.
    float bias[4];
    int   cols[4];
    #pragma unroll
    for (int n = 0; n < 4; ++n) {
        const int c = v0 + n * 16 + (lane & 15);
        cols[n] = c;
        bias[n] = (c < V) ? b_out[c] : 0.f;
    }
    const int rbase = wid * 128 + (lane >> 4) * 4;
    #pragma unroll
    for (int m = 0; m < 8; ++m) {
        #pragma unroll
        for (int r = 0; r < 4; ++r) {
            const int row = rbase + m * 16 + r;
            float* dst = logit + (size_t)row * V;
            #pragma unroll
            for (int n = 0; n < 4; ++n) {
                if (cols[n] < V)
                    dst[cols[n]] = fast_tanh(acc[m][n][r] + bias[n]);
            }
        }
    }
}

// ---------------------------------------------------------------------------
// Fallback kernel (round-4, proven): reg-staged split-bf16 GEMM, used only if
// ws_size can't hold the h planes.
// ---------------------------------------------------------------------------
#define BM  64
#define BN  128
#define NVB 782   // ceil(V/BN)
#define NBB 8     // B/BM

__global__ __launch_bounds__(256) void out_gemm_mfma_reg(
    const float* __restrict__ hnew,
    const float* __restrict__ w_out,
    const float* __restrict__ b_out,
    float*       __restrict__ logit)
{
    __shared__ unsigned short w_hi[BN * BK];
    __shared__ unsigned short w_lo[BN * BK];
    __shared__ unsigned short h_hi[BM * BK];
    __shared__ unsigned short h_lo[BM * BK];

    const int tid  = threadIdx.x;
    const int lane = tid & 63;
    const int wid  = tid >> 6;
    const int wm   = wid >> 1;
    const int wn   = wid & 1;

    const int bid = blockIdx.x;
    const int wg  = (bid & 7) * NVB + (bid >> 3);
    const int bx  = wg & 7;
    const int by  = wg >> 3;
    const int b0  = bx * BM;
    const int v0  = by * BN;

    float4 wreg[8];
    float4 hreg[4];

    auto load_chunk = [&](int k0) {
        #pragma unroll
        for (int i = 0; i < 8; ++i) {
            const int idx4 = i * 256 + tid;
            const int row  = idx4 >> 4;
            const int k4   = (idx4 & 15) << 2;
            int vg = v0 + row; if (vg > V - 1) vg = V - 1;
            wreg[i] = *reinterpret_cast<const float4*>(&w_out[(size_t)vg * H + k0 + k4]);
        }
        #pragma unroll
        for (int i = 0; i < 4; ++i) {
            const int idx4 = i * 256 + tid;
            const int row  = idx4 >> 4;
            const int k4   = (idx4 & 15) << 2;
            hreg[i] = *reinterpret_cast<const float4*>(&hnew[(b0 + row) * H + k0 + k4]);
        }
    };

    auto store_chunk = [&]() {
        #pragma unroll
        for (int i = 0; i < 8; ++i) {
            const int idx4 = i * 256 + tid;
            const int row  = idx4 >> 4;
            const int k4   = (idx4 & 15) << 2;
            const int off  = row * (BK * 2) + ((k4 * 2) ^ ((row & 7) << 4));
            const float f[4] = {wreg[i].x, wreg[i].y, wreg[i].z, wreg[i].w};
            unsigned short hv[4], lv[4];
            #pragma unroll
            for (int j = 0; j < 4; ++j) {
                hv[j] = f32_bf16_rne(f[j]);
                lv[j] = f32_bf16_rne(f[j] - bf16u_f32(hv[j]));
            }
            *reinterpret_cast<ushort4*>(reinterpret_cast<char*>(w_hi) + off) =
                make_ushort4(hv[0], hv[1], hv[2], hv[3]);
            *reinterpret_cast<ushort4*>(reinterpret_cast<char*>(w_lo) + off) =
                make_ushort4(lv[0], lv[1], lv[2], lv[3]);
        }
        #pragma unroll
        for (int i = 0; i < 4; ++i) {
            const int idx4 = i * 256 + tid;
            const int row  = idx4 >> 4;
            const int k4   = (idx4 & 15) << 2;
            const int off  = row * (BK * 2) + ((k4 * 2) ^ ((row & 7) << 4));
            const float f[4] = {hreg[i].x, hreg[i].y, hreg[i].z, hreg[i].w};
            unsigned short hv[4], lv[4];
            #pragma unroll
            for (int j = 0; j < 4; ++j) {
                hv[j] = f32_bf16_rne(f[j]);
                lv[j] = f32_bf16_rne(f[j] - bf16u_f32(hv[j]));
            }
            *reinterpret_cast<ushort4*>(reinterpret_cast<char*>(h_hi) + off) =
                make_ushort4(hv[0], hv[1], hv[2], hv[3]);
            *reinterpret_cast<ushort4*>(reinterpret_cast<char*>(h_lo) + off) =
                make_ushort4(lv[0], lv[1], lv[2], lv[3]);
        }
    };

    f32x4 acc[2][4];
    #pragma unroll
    for (int i = 0; i < 2; ++i)
        #pragma unroll
        for (int n = 0; n < 4; ++n)
            acc[i][n] = f32x4{0.f, 0.f, 0.f, 0.f};

    auto compute = [&]() {
        #pragma unroll
        for (int ks = 0; ks < 2; ++ks) {
            const int kb = ks * 64 + (lane >> 4) * 16;
            bf16x8 ah[2], al[2];
            #pragma unroll
            for (int i = 0; i < 2; ++i) {
                const int row = wm * 32 + i * 16 + (lane & 15);
                const int off = row * (BK * 2) + (kb ^ ((row & 7) << 4));
                ah[i] = *reinterpret_cast<const bf16x8*>(
                            reinterpret_cast<const char*>(h_hi) + off);
                al[i] = *reinterpret_cast<const bf16x8*>(
                            reinterpret_cast<const char*>(h_lo) + off);
            }
            #pragma unroll
            for (int n = 0; n < 4; ++n) {
                const int row = wn * 64 + n * 16 + (lane & 15);
                const int off = row * (BK * 2) + (kb ^ ((row & 7) << 4));
                const bf16x8 bh = *reinterpret_cast<const bf16x8*>(
                            reinterpret_cast<const char*>(w_hi) + off);
                const bf16x8 bl = *reinterpret_cast<const bf16x8*>(
                            reinterpret_cast<const char*>(w_lo) + off);
                #pragma unroll
                for (int i = 0; i < 2; ++i) {
                    acc[i][n] = __builtin_amdgcn_mfma_f32_16x16x32_bf16(ah[i], bh, acc[i][n], 0, 0, 0);
                    acc[i][n] = __builtin_amdgcn_mfma_f32_16x16x32_bf16(ah[i], bl, acc[i][n], 0, 0, 0);
                    acc[i][n] = __builtin_amdgcn_mfma_f32_16x16x32_bf16(al[i], bh, acc[i][n], 0, 0, 0);
                }
            }
        }
    };

    load_chunk(0);
    store_chunk();
    __syncthreads();
    for (int t = 0; t < 4; ++t) {
        if (t < 3) load_chunk((t + 1) * BK);
        compute();
        __syncthreads();
        if (t < 3) { store_chunk(); __syncthreads(); }
    }

    float bias[4];
    int   cols[4];
    #pragma unroll
    for (int n = 0; n < 4; ++n) {
        const int c = v0 + wn * 64 + n * 16 + (lane & 15);
        cols[n] = c;
        bias[n] = (c < V) ? b_out[c] : 0.f;
    }
    const int rbase = b0 + wm * 32 + (lane >> 4) * 4;
    #pragma unroll
    for (int i = 0; i < 2; ++i) {
        #pragma unroll
        for (int r = 0; r < 4; ++r) {
            const int row = rbase + i * 16 + r;
            float* dst = logit + (size_t)row * V;
            #pragma unroll
            for (int n = 0; n < 4; ++n) {
                if (cols[n] < V)
                    dst[cols[n]] = tanhf(acc[i][n][r] + bias[n]);
            }
        }
    }
}

// ---------------------------------------------------------------------------
extern "C" void kernel_launch(void* const* d_in, const int* in_sizes, int n_in,
                              void* d_out, int out_size, void* d_ws, size_t ws_size,
                              hipStream_t stream) {
    const int*   input  = (const int*)  d_in[0];
    // d_in[1] = target (unused by forward)
    const float* hidden = (const float*)d_in[2];
    const float* w_ih   = (const float*)d_in[3];
    const float* w_hh   = (const float*)d_in[4];
    const float* b_ih   = (const float*)d_in[5];
    const float* b_hh   = (const float*)d_in[6];
    const float* w_out  = (const float*)d_in[7];
    const float* b_out  = (const float*)d_in[8];

    float* out   = (float*)d_out;
    float* logit = out;                      // first B*V floats
    float* h_new = out + (size_t)B * V;      // then L*B*H floats (L=1)

    const size_t nh = (size_t)B * H;                          // 131,072
    const size_t needed = 2 * nh * sizeof(unsigned short);    // 512 KB

    if (ws_size >= needed) {
        unsigned short* hhi = (unsigned short*)d_ws;
        unsigned short* hlo = hhi + nh;

        gru_cell_kernel<<<B, 256, 0, stream>>>(input, hidden, w_ih, w_hh,
                                               b_ih, b_hh, h_new, hhi, hlo);
        out_gemm_fused<<<NVB2, 256, 0, stream>>>(w_out, hhi, hlo, b_out, logit);
    } else {
        gru_cell_kernel<<<B, 256, 0, stream>>>(input, hidden, w_ih, w_hh,
                                               b_ih, b_hh, h_new,
                                               nullptr, nullptr);
        out_gemm_mfma_reg<<<NVB * NBB, 256, 0, stream>>>(h_new, w_out,
                                                         b_out, logit);
    }
}